// Round 1
// baseline (545.210 us; speedup 1.0000x reference)
//
#include <hip/hip_runtime.h>
#include <math.h>

#define BS 32
#define REACH 2
#define CI 12
#define NHID 15
#define NBLK 6144                 // 8*3*16*16 blocks of 32x32
#define NPIX (NBLK * 1024)        // 6291456 pixels

__global__ __launch_bounds__(1024) void codec_main(
    const float* __restrict__ x,
    const float* __restrict__ Wh,   // [NHID][CI][CI]
    const float* __restrict__ bh,   // [NHID][CI]
    const float* __restrict__ Wo,   // [CI]
    const float* __restrict__ bo,   // [1]
    float* __restrict__ out,        // [1 + NPIX]
    float* __restrict__ loss_acc)   // [1] pre-zeroed
{
    __shared__ float tile[36][37];  // 32x32 block + 2-halo, +1 col pad
    __shared__ float wsum[16];

    const int n   = blockIdx.x;     // global block id 0..6143
    const int tid = threadIdx.x;    // 0..1023
    const int y    = tid >> 5;
    const int xcol = tid & 31;

    // zero the whole padded tile (halo must be 0, per-block padding)
    for (int i = tid; i < 36 * 37; i += 1024) ((float*)tile)[i] = 0.0f;
    __syncthreads();

    const int bc  = n >> 8;         // b*3+c, 0..23
    const int blk = n & 255;
    const int by  = blk >> 4;
    const int bx  = blk & 15;

    const float v = x[((size_t)bc * 512 + (size_t)(by * 32 + y)) * 512
                      + (size_t)(bx * 32 + xcol)];
    tile[y + 2][xcol + 2] = v;
    __syncthreads();

    // causal neighborhood offsets, reference order
    float h[CI];
    {
        const int yy = y + 2, xx = xcol + 2;
        h[0]  = tile[yy - 2][xx - 2];
        h[1]  = tile[yy - 2][xx - 1];
        h[2]  = tile[yy - 2][xx + 0];
        h[3]  = tile[yy - 2][xx + 1];
        h[4]  = tile[yy - 2][xx + 2];
        h[5]  = tile[yy - 1][xx - 2];
        h[6]  = tile[yy - 1][xx - 1];
        h[7]  = tile[yy - 1][xx + 0];
        h[8]  = tile[yy - 1][xx + 1];
        h[9]  = tile[yy - 1][xx + 2];
        h[10] = tile[yy + 0][xx - 2];
        h[11] = tile[yy + 0][xx - 1];
    }

    // 15 hidden layers, 12->12, leaky_relu(0.01)
    for (int l = 0; l < NHID; ++l) {
        const float* __restrict__ W = Wh + l * CI * CI;
        const float* __restrict__ B = bh + l * CI;
        float nh[CI];
        #pragma unroll
        for (int o = 0; o < CI; ++o) {
            float acc = B[o];
            #pragma unroll
            for (int i = 0; i < CI; ++i) acc = fmaf(h[i], W[o * CI + i], acc);
            nh[o] = fmaxf(acc, 0.01f * acc);   // leaky_relu
        }
        #pragma unroll
        for (int o = 0; o < CI; ++o) h[o] = nh[o];
    }

    // linear head + clip
    float pred = bo[0];
    #pragma unroll
    for (int i = 0; i < CI; ++i) pred = fmaf(h[i], Wo[i], pred);
    pred = fminf(fmaxf(pred, -1.0f), 1.0f);

    const float delta = fmodf(v - pred + 1.0f, 2.0f) - 1.0f;
    out[1 + (size_t)n * 1024 + tid] = delta;

    // block-level sum of squares for loss
    float d2 = delta * delta;
    #pragma unroll
    for (int off = 32; off > 0; off >>= 1) d2 += __shfl_down(d2, off, 64);
    const int lane = tid & 63;
    const int w    = tid >> 6;
    if (lane == 0) wsum[w] = d2;
    __syncthreads();
    if (tid < 16) {
        float s = wsum[tid];
        #pragma unroll
        for (int off = 8; off > 0; off >>= 1) s += __shfl_down(s, off, 16);
        if (tid == 0) atomicAdd(loss_acc, s);
    }
}

__global__ void codec_loss(const float* __restrict__ acc, float* __restrict__ out)
{
    out[0] = 255.0f * sqrtf(acc[0] / (float)NPIX);
}

extern "C" void kernel_launch(void* const* d_in, const int* in_sizes, int n_in,
                              void* d_out, int out_size, void* d_ws, size_t ws_size,
                              hipStream_t stream)
{
    const float* x  = (const float*)d_in[0];
    const float* Wh = (const float*)d_in[1];
    const float* bh = (const float*)d_in[2];
    const float* Wo = (const float*)d_in[3];
    const float* bo = (const float*)d_in[4];
    float* out = (float*)d_out;
    float* acc = (float*)d_ws;

    hipMemsetAsync(acc, 0, sizeof(float), stream);   // graph-capture safe
    codec_main<<<NBLK, 1024, 0, stream>>>(x, Wh, bh, Wo, bo, out, acc);
    codec_loss<<<1, 1, 0, stream>>>(acc, out);
}

// Round 2
// 458.784 us; speedup vs baseline: 1.1884x; 1.1884x over previous
//
#include <hip/hip_runtime.h>
#include <math.h>

#define BS 32
#define REACH 2
#define CI 12
#define NHID 15
#define NBLK 6144                 // 8*3*16*16 blocks of 32x32
#define NPIX (NBLK * 1024)        // 6291456 pixels
#define P 4                       // pixels per thread

__global__ __launch_bounds__(256) void codec_main(
    const float* __restrict__ x,
    const float* __restrict__ Wh,   // [NHID][CI][CI]
    const float* __restrict__ bh,   // [NHID][CI]
    const float* __restrict__ Wo,   // [CI]
    const float* __restrict__ bo,   // [1]
    float* __restrict__ out,        // [1 + NPIX]
    float* __restrict__ loss_acc)   // [1] pre-zeroed
{
    __shared__ float tile[36][37];  // 32x32 block + 2-halo, +1 col pad
    __shared__ float wsum[4];

    const int n   = blockIdx.x;     // global block id 0..6143
    const int tid = threadIdx.x;    // 0..255
    const int col = tid & 31;
    const int r0  = tid >> 5;       // 0..7

    // zero the whole padded tile (halo must be 0: per-block zero padding)
    #pragma unroll
    for (int i = 0; i < 6; ++i) {
        int idx = tid + i * 256;
        if (idx < 36 * 37) ((float*)tile)[idx] = 0.0f;
    }
    __syncthreads();

    const int bc  = n >> 8;         // b*3+c, 0..23
    const int blk = n & 255;
    const int by  = blk >> 4;
    const int bx  = blk & 15;

    float v[P];
    #pragma unroll
    for (int p = 0; p < P; ++p) {
        const int row = r0 + 8 * p;
        v[p] = x[((size_t)bc * 512 + (size_t)(by * 32 + row)) * 512
                 + (size_t)(bx * 32 + col)];
        tile[row + 2][col + 2] = v[p];
    }
    __syncthreads();

    // causal neighborhood gather (reference offset order)
    float h[P][CI];
    #pragma unroll
    for (int p = 0; p < P; ++p) {
        const int yy = r0 + 8 * p + 2, xx = col + 2;
        h[p][0]  = tile[yy - 2][xx - 2];
        h[p][1]  = tile[yy - 2][xx - 1];
        h[p][2]  = tile[yy - 2][xx + 0];
        h[p][3]  = tile[yy - 2][xx + 1];
        h[p][4]  = tile[yy - 2][xx + 2];
        h[p][5]  = tile[yy - 1][xx - 2];
        h[p][6]  = tile[yy - 1][xx - 1];
        h[p][7]  = tile[yy - 1][xx + 0];
        h[p][8]  = tile[yy - 1][xx + 1];
        h[p][9]  = tile[yy - 1][xx + 2];
        h[p][10] = tile[yy + 0][xx - 2];
        h[p][11] = tile[yy + 0][xx - 1];
    }

    // 15 hidden layers, 12->12, leaky_relu(0.01)
    for (int l = 0; l < NHID; ++l) {
        const float* __restrict__ W = Wh + l * CI * CI;
        const float* __restrict__ B = bh + l * CI;
        float nh[P][CI];
        #pragma unroll
        for (int o = 0; o < CI; ++o) {
            const float b = B[o];
            float acc[P];
            #pragma unroll
            for (int p = 0; p < P; ++p) acc[p] = b;
            #pragma unroll
            for (int i = 0; i < CI; ++i) {
                const float w = W[o * CI + i];     // wave-uniform -> SGPR
                #pragma unroll
                for (int p = 0; p < P; ++p)
                    acc[p] = fmaf(h[p][i], w, acc[p]);
            }
            #pragma unroll
            for (int p = 0; p < P; ++p)
                nh[p][o] = fmaxf(acc[p], 0.01f * acc[p]);   // leaky_relu
        }
        #pragma unroll
        for (int o = 0; o < CI; ++o)
            #pragma unroll
            for (int p = 0; p < P; ++p) h[p][o] = nh[p][o];
    }

    // linear head + clip + fmod delta
    float d2sum = 0.0f;
    const float bo0 = bo[0];
    #pragma unroll
    for (int p = 0; p < P; ++p) {
        float pred = bo0;
        #pragma unroll
        for (int i = 0; i < CI; ++i) pred = fmaf(h[p][i], Wo[i], pred);
        pred = fminf(fmaxf(pred, -1.0f), 1.0f);
        const float delta = fmodf(v[p] - pred + 1.0f, 2.0f) - 1.0f;
        out[1 + (size_t)n * 1024 + (size_t)((r0 + 8 * p) * 32 + col)] = delta;
        d2sum = fmaf(delta, delta, d2sum);
    }

    // block-level sum of squares for loss
    #pragma unroll
    for (int off = 32; off > 0; off >>= 1) d2sum += __shfl_down(d2sum, off, 64);
    const int lane = tid & 63;
    const int wid  = tid >> 6;
    if (lane == 0) wsum[wid] = d2sum;
    __syncthreads();
    if (tid == 0) {
        const float s = wsum[0] + wsum[1] + wsum[2] + wsum[3];
        atomicAdd(loss_acc, s);
    }
}

__global__ void codec_loss(const float* __restrict__ acc, float* __restrict__ out)
{
    out[0] = 255.0f * sqrtf(acc[0] / (float)NPIX);
}

extern "C" void kernel_launch(void* const* d_in, const int* in_sizes, int n_in,
                              void* d_out, int out_size, void* d_ws, size_t ws_size,
                              hipStream_t stream)
{
    const float* x  = (const float*)d_in[0];
    const float* Wh = (const float*)d_in[1];
    const float* bh = (const float*)d_in[2];
    const float* Wo = (const float*)d_in[3];
    const float* bo = (const float*)d_in[4];
    float* out = (float*)d_out;
    float* acc = (float*)d_ws;

    hipMemsetAsync(acc, 0, sizeof(float), stream);   // graph-capture safe
    codec_main<<<NBLK, 256, 0, stream>>>(x, Wh, bh, Wo, bo, out, acc);
    codec_loss<<<1, 1, 0, stream>>>(acc, out);
}